// Round 10
// baseline (928.163 us; speedup 1.0000x reference)
//
#include <hip/hip_runtime.h>
#include <hip/hip_bf16.h>

#define N 8192
#define D_IN 512
#define D_OUT 64
#define ALPHA 0.2f
#define BM 16
#define NSPLIT 4
#define KSEG (N / NSPLIT)       // 2048 cols per split
#define NSH (KSEG / 128)        // 16 steps/block; each wave does 32 cols/step
#define REP 8                   // DIAGNOSTIC: x8 internal repeat to surface in rocprof top-5

typedef __attribute__((ext_vector_type(4))) float f32x4;
typedef __attribute__((ext_vector_type(8))) short bf16x8;

static __device__ __forceinline__ unsigned pk_bf16(float lo, float hi) {
    unsigned ulo = __bfloat16_as_ushort(__float2bfloat16(lo));
    unsigned uhi = __bfloat16_as_ushort(__float2bfloat16(hi));
    return (uhi << 16) | ulo;
}

// Kernel 1 (fused): blocks [0,512): h = input @ W -> pre-swizzled MFMA B-frags
// (hpk) + s1 = h@a1, s2 = h@a2. Blocks [512, 2560): adj -> 1-bit/elem mask.
// DIAGNOSTIC: whole body repeated REP times (identical stores).
__global__ __launch_bounds__(256) void gat_prep_kernel(
    const float* __restrict__ input, const float* __restrict__ adj,
    const float* __restrict__ W, const float* __restrict__ a,
    unsigned short* __restrict__ hpk, float* __restrict__ s1,
    float* __restrict__ s2, unsigned char* __restrict__ msk)
{
    for (int rep = 0; rep < REP; ++rep) {
    if (blockIdx.x < 512) {
        int wave = (blockIdx.x * 256 + threadIdx.x) >> 6;
        int lane = threadIdx.x & 63;
        int row0 = wave * 4;
        const float* in0 = input + (size_t)row0 * D_IN;
        float a1 = a[lane], a2 = a[D_OUT + lane];
        float acc[4];
#pragma unroll
        for (int r = 0; r < 4; ++r) acc[r] = 0.f;
#pragma unroll 4
        for (int k = 0; k < D_IN; ++k) {
            float wk = W[k * D_OUT + lane];
#pragma unroll
            for (int r = 0; r < 4; ++r)
                acc[r] = fmaf(in0[(size_t)r * D_IN + k], wk, acc[r]);
        }
        {
            int kw = row0 >> 5, kb = (row0 >> 3) & 3, e0 = row0 & 7;
            int dw = lane >> 4, dd = lane & 15;
            size_t off = ((size_t)((kw * 4 + dw) * 64) + kb * 16 + dd) * 8 + e0;
            uint2 hv;
            hv.x = pk_bf16(acc[0], acc[1]);
            hv.y = pk_bf16(acc[2], acc[3]);
            *(uint2*)(hpk + off) = hv;
        }
#pragma unroll
        for (int r = 0; r < 4; ++r) {
            float p1 = acc[r] * a1;
            float p2 = acc[r] * a2;
#pragma unroll
            for (int off = 32; off; off >>= 1) {
                p1 += __shfl_xor(p1, off, 64);
                p2 += __shfl_xor(p2, off, 64);
            }
            if (lane == 0) { s1[row0 + r] = p1; s2[row0 + r] = p2; }
        }
    } else {
        size_t wave = (((size_t)blockIdx.x - 512) * 256 + threadIdx.x) >> 6;
        int lane = threadIdx.x & 63;
#pragma unroll 4
        for (int it = 0; it < 16; ++it) {
            size_t fo = (wave * 16 + it) * 512 + (size_t)lane * 8;
            float4 v0 = *(const float4*)(adj + fo);
            float4 v1 = *(const float4*)(adj + fo + 4);
            unsigned b =  (unsigned)(v0.x > 0.f)
                       | ((unsigned)(v0.y > 0.f) << 1)
                       | ((unsigned)(v0.z > 0.f) << 2)
                       | ((unsigned)(v0.w > 0.f) << 3)
                       | ((unsigned)(v1.x > 0.f) << 4)
                       | ((unsigned)(v1.y > 0.f) << 5)
                       | ((unsigned)(v1.z > 0.f) << 6)
                       | ((unsigned)(v1.w > 0.f) << 7);
            msk[fo >> 3] = (unsigned char)b;
        }
    }
    }  // rep
}

struct MSP { unsigned m; float4 sA, sB; };   // mask byte + s2 pair for one 32-col slice
struct UBP { uint4 b0, b1, b2, b3; };        // 4 d-window B-fragments for one 32-k window

static __device__ __forceinline__ void issue_ms(MSP& p, const unsigned char* mb,
                                                const float* sb, int ps) {
    p.m  = mb[ps * 16];
    p.sA = *(const float4*)(sb + ps * 128);
    p.sB = *(const float4*)(sb + ps * 128 + 4);
}
static __device__ __forceinline__ void issue_ub(UBP& p, const unsigned short* hb,
                                                int ps) {
    const unsigned short* f = hb + ((size_t)ps << 13);
    p.b0 = *(const uint4*)(f);
    p.b1 = *(const uint4*)(f + 512);
    p.b2 = *(const uint4*)(f + 1024);
    p.b3 = *(const uint4*)(f + 1536);
}

// Kernel 2: masked-softmax @ h via MFMA — barrier-free, all inputs L2-resident.
// DIAGNOSTIC: whole body repeated REP times (identical stores).
__global__ __launch_bounds__(256, 4) void gat_flash_kernel(
    const unsigned char* __restrict__ msk, const unsigned short* __restrict__ hpk,
    const float* __restrict__ s1, const float* __restrict__ s2,
    float* __restrict__ pacc, float* __restrict__ plsum)
{
    __shared__ float Cl[4][BM][D_OUT];   // 16 KB, used once at end
    __shared__ float lsl[4][BM];

    for (int rep = 0; rep < REP; ++rep) {
    const int tid  = threadIdx.x;
    const int lane = tid & 63;
    const int ws   = tid >> 6;
    const int i    = lane & 15;
    const int kb   = lane >> 4;
    const int hf   = blockIdx.x >> 9;
    const int rb   = blockIdx.x & 511;
    const int rg   = rb * BM + i;

    const int col0 = hf * KSEG + ws * 32 + kb * 8;
    const unsigned char* mb_lane = msk + ((size_t)rg << 10) + (col0 >> 3);
    const float* s2_lane = s2 + col0;
    const unsigned short* hb_lane =
        hpk + (((size_t)(hf * 64 + ws)) << 11) + (lane << 3);

    float s1r  = s1[rg];
    float eref = s1r + s2[rg];
    eref = eref > 0.f ? eref : ALPHA * eref;
    float lsum = 0.f;
    f32x4 acc0 = {0,0,0,0}, acc1 = {0,0,0,0}, acc2 = {0,0,0,0}, acc3 = {0,0,0,0};

    auto step = [&](const MSP& p, const UBP& u) {
        const float* sv0 = (const float*)&p.sA;
        const float* sv1 = (const float*)&p.sB;
        float w[8];
#pragma unroll
        for (int z = 0; z < 4; ++z) {
            float e0 = s1r + sv0[z]; e0 = e0 > 0.f ? e0 : ALPHA * e0;
            float e1 = s1r + sv1[z]; e1 = e1 > 0.f ? e1 : ALPHA * e1;
            float w0 = __expf(e0 - eref);
            float w1 = __expf(e1 - eref);
            w[z]     = ((p.m >> z) & 1u)       ? w0 : 0.f;
            w[z + 4] = ((p.m >> (z + 4)) & 1u) ? w1 : 0.f;
        }
#pragma unroll
        for (int z = 0; z < 8; ++z) lsum += w[z];
        uint4 pk;
        pk.x = pk_bf16(w[0], w[1]); pk.y = pk_bf16(w[2], w[3]);
        pk.z = pk_bf16(w[4], w[5]); pk.w = pk_bf16(w[6], w[7]);
        bf16x8 A = __builtin_bit_cast(bf16x8, pk);
        acc0 = __builtin_amdgcn_mfma_f32_16x16x32_bf16(A, __builtin_bit_cast(bf16x8, u.b0), acc0, 0, 0, 0);
        acc1 = __builtin_amdgcn_mfma_f32_16x16x32_bf16(A, __builtin_bit_cast(bf16x8, u.b1), acc1, 0, 0, 0);
        acc2 = __builtin_amdgcn_mfma_f32_16x16x32_bf16(A, __builtin_bit_cast(bf16x8, u.b2), acc2, 0, 0, 0);
        acc3 = __builtin_amdgcn_mfma_f32_16x16x32_bf16(A, __builtin_bit_cast(bf16x8, u.b3), acc3, 0, 0, 0);
    };

    MSP M0, M1; UBP U0, U1;
    issue_ms(M0, mb_lane, s2_lane, 0); issue_ub(U0, hb_lane, 0);
    issue_ms(M1, mb_lane, s2_lane, 1); issue_ub(U1, hb_lane, 1);
#pragma unroll 2
    for (int p = 0; p < NSH; p += 2) {
        step(M0, U0);
        if (p + 2 < NSH) { issue_ms(M0, mb_lane, s2_lane, p + 2); issue_ub(U0, hb_lane, p + 2); }
        step(M1, U1);
        if (p + 3 < NSH) { issue_ms(M1, mb_lane, s2_lane, p + 3); issue_ub(U1, hb_lane, p + 3); }
    }

    lsum += __shfl_xor(lsum, 16, 64);
    lsum += __shfl_xor(lsum, 32, 64);
    if (lane < 16) lsl[ws][lane] = lsum;

    const f32x4 av[4] = {acc0, acc1, acc2, acc3};
#pragma unroll
    for (int dw = 0; dw < 4; ++dw)
#pragma unroll
        for (int reg = 0; reg < 4; ++reg)
            Cl[ws][kb * 4 + reg][dw * 16 + i] = av[dw][reg];
    __syncthreads();

#pragma unroll
    for (int o = tid; o < BM * D_OUT; o += 256) {
        int row = o >> 6, d = o & 63;
        float v = (Cl[0][row][d] + Cl[1][row][d]) + (Cl[2][row][d] + Cl[3][row][d]);
        pacc[((size_t)hf * N + rb * BM + row) * 64 + d] = v;
    }
    if (tid < BM)
        plsum[hf * N + rb * BM + tid] =
            (lsl[0][tid] + lsl[1][tid]) + (lsl[2][tid] + lsl[3][tid]);
    __syncthreads();   // protect Cl/lsl before next rep overwrites
    }  // rep
}

// Kernel 3: combine the 4 k-splits, normalize, elu.
__global__ __launch_bounds__(256) void gat_reduce_kernel(
    const float* __restrict__ pacc, const float* __restrict__ plsum,
    float* __restrict__ out)
{
    int idx = blockIdx.x * 256 + threadIdx.x;
    int row = idx >> 6;
    float aa = 0.f, l = 0.f;
#pragma unroll
    for (int hf = 0; hf < NSPLIT; ++hf) {
        aa += pacc[(size_t)hf * N * 64 + idx];
        l  += plsum[hf * N + row];
    }
    float o = aa / l;
    out[idx] = o > 0.f ? o : expm1f(o);
}

extern "C" void kernel_launch(void* const* d_in, const int* in_sizes, int n_in,
                              void* d_out, int out_size, void* d_ws, size_t ws_size,
                              hipStream_t stream) {
    const float* input = (const float*)d_in[0];   // (8192, 512) f32
    const float* adj   = (const float*)d_in[1];   // (8192, 8192) f32
    const float* W     = (const float*)d_in[2];   // (512, 64) f32
    const float* a     = (const float*)d_in[3];   // (128, 1) f32
    float* out = (float*)d_out;                   // (8192, 64) f32

    unsigned short* hpk = (unsigned short*)d_ws;          // 1 MB fragment buffer
    float* s1    = (float*)(hpk + (size_t)N * D_OUT);     // N f32
    float* s2    = s1 + N;                                // N f32
    float* pacc  = s2 + N;                                // NSPLIT*N*64 f32 = 8 MB
    float* plsum = pacc + (size_t)NSPLIT * N * 64;        // NSPLIT*N f32
    unsigned char* msk = (unsigned char*)(plsum + NSPLIT * N);  // N*N/8 = 8 MB

    gat_prep_kernel<<<2560, 256, 0, stream>>>(input, adj, W, a, hpk, s1, s2, msk);
    gat_flash_kernel<<<512 * NSPLIT, 256, 0, stream>>>(msk, hpk, s1, s2, pacc, plsum);
    gat_reduce_kernel<<<N * 64 / 256, 256, 0, stream>>>(pacc, plsum, out);
}

// Round 11
// 139.916 us; speedup vs baseline: 6.6337x; 6.6337x over previous
//
#include <hip/hip_runtime.h>
#include <hip/hip_bf16.h>

#define N 8192
#define D_IN 512
#define D_OUT 64
#define ALPHA 0.2f
#define BM 64
#define NSPLIT 4
#define KSEG (N / NSPLIT)       // 2048 cols per split
#define NSH (KSEG / 128)        // 16 steps; each wave covers 32 cols/step
#define NSLICE (NSPLIT * 4)     // pacc slices: 4 k-splits x 4 waves

typedef __attribute__((ext_vector_type(4))) float f32x4;
typedef __attribute__((ext_vector_type(8))) short bf16x8;

static __device__ __forceinline__ unsigned pk_bf16(float lo, float hi) {
    unsigned ulo = __bfloat16_as_ushort(__float2bfloat16(lo));
    unsigned uhi = __bfloat16_as_ushort(__float2bfloat16(hi));
    return (uhi << 16) | ulo;
}

// Kernel 1a: pure adj -> bitmask stream. One dispatch, no branches, no
// cross-lane, no LDS: msk[f>>3] bit z = adj[f+z] > 0. 4096 blocks x 4 waves,
// 8 iters/wave (2 KB/wave/iter).
__global__ __launch_bounds__(256) void gat_mask_kernel(
    const float* __restrict__ adj, unsigned char* __restrict__ msk)
{
    size_t wave = ((size_t)blockIdx.x * 256 + threadIdx.x) >> 6;
    int lane = threadIdx.x & 63;
#pragma unroll
    for (int it = 0; it < 8; ++it) {
        size_t fo = (wave * 8 + it) * 512 + (size_t)lane * 8;
        float4 v0 = *(const float4*)(adj + fo);
        float4 v1 = *(const float4*)(adj + fo + 4);
        unsigned b =  (unsigned)(v0.x > 0.f)
                   | ((unsigned)(v0.y > 0.f) << 1)
                   | ((unsigned)(v0.z > 0.f) << 2)
                   | ((unsigned)(v0.w > 0.f) << 3)
                   | ((unsigned)(v1.x > 0.f) << 4)
                   | ((unsigned)(v1.y > 0.f) << 5)
                   | ((unsigned)(v1.z > 0.f) << 6)
                   | ((unsigned)(v1.w > 0.f) << 7);
        msk[fo >> 3] = (unsigned char)b;
    }
}

// Kernel 1b: h = input @ W -> pre-swizzled MFMA B-frags (hpk) + s1/s2.
// K-split x4: wave ws does k in [ws*128,+128) for 4 rows; LDS combine;
// wave 0 packs + reduces. 2048 blocks -> 8 blocks/CU.
__global__ __launch_bounds__(256) void gat_h_kernel(
    const float* __restrict__ input, const float* __restrict__ W,
    const float* __restrict__ a, unsigned short* __restrict__ hpk,
    float* __restrict__ s1, float* __restrict__ s2)
{
    __shared__ float hp[4][4][64];      // [ws][row][d] partials, 4 KB
    int ws   = threadIdx.x >> 6;
    int lane = threadIdx.x & 63;
    int row0 = blockIdx.x * 4;
    const float* in0 = input + (size_t)row0 * D_IN + ws * 128;
    const float* Wp  = W + ws * 128 * D_OUT;
    float acc[4] = {0.f, 0.f, 0.f, 0.f};
#pragma unroll 4
    for (int k = 0; k < 128; ++k) {
        float wk = Wp[k * D_OUT + lane];
#pragma unroll
        for (int r = 0; r < 4; ++r)
            acc[r] = fmaf(in0[r * D_IN + k], wk, acc[r]);   // in0 wave-uniform
    }
#pragma unroll
    for (int r = 0; r < 4; ++r) hp[ws][r][lane] = acc[r];
    __syncthreads();
    if (ws == 0) {
        float h[4];
#pragma unroll
        for (int r = 0; r < 4; ++r)
            h[r] = (hp[0][r][lane] + hp[1][r][lane]) + (hp[2][r][lane] + hp[3][r][lane]);
        // hpk fragment store: element (j,d) -> ((kw*4+dw)*64 + kb*16+dd)*8 + e
        int kw = row0 >> 5, kb = (row0 >> 3) & 3, e0 = row0 & 7;
        int dw = lane >> 4, dd = lane & 15;
        size_t off = ((size_t)((kw * 4 + dw) * 64) + kb * 16 + dd) * 8 + e0;
        uint2 hv;
        hv.x = pk_bf16(h[0], h[1]);
        hv.y = pk_bf16(h[2], h[3]);
        *(uint2*)(hpk + off) = hv;
        float a1 = a[lane], a2 = a[D_OUT + lane];
#pragma unroll
        for (int r = 0; r < 4; ++r) {
            float p1 = h[r] * a1;
            float p2 = h[r] * a2;
#pragma unroll
            for (int off2 = 32; off2; off2 >>= 1) {
                p1 += __shfl_xor(p1, off2, 64);
                p2 += __shfl_xor(p2, off2, 64);
            }
            if (lane == 0) { s1[row0 + r] = p1; s2[row0 + r] = p2; }
        }
    }
}

struct MSP { unsigned m[4]; float4 sA, sB; };   // 4 mask bytes (per ag) + s2 pair
struct UBP { uint4 b0, b1, b2, b3; };           // 4 d-window B-frags for one 32-k window

static __device__ __forceinline__ void issue_ms(MSP& p,
    const unsigned char* m0, const unsigned char* m1,
    const unsigned char* m2, const unsigned char* m3,
    const float* sb, int ps) {
    p.m[0] = m0[ps * 16];
    p.m[1] = m1[ps * 16];
    p.m[2] = m2[ps * 16];
    p.m[3] = m3[ps * 16];
    p.sA = *(const float4*)(sb + ps * 128);
    p.sB = *(const float4*)(sb + ps * 128 + 4);
}
static __device__ __forceinline__ void issue_ub(UBP& p, const unsigned short* hb,
                                                int ps) {
    const unsigned short* f = hb + ((size_t)ps << 13);
    p.b0 = *(const uint4*)(f);
    p.b1 = *(const uint4*)(f + 512);
    p.b2 = *(const uint4*)(f + 1024);
    p.b3 = *(const uint4*)(f + 1536);
}

// Kernel 2: masked-softmax @ h via MFMA — barrier-free, BM=64 rows/block.
// Grid = 128 rowblocks x 4 k-splits = 512. Wave ws owns 32-col slices; per step:
// 4 row-groups (ag) x w[8] natively as MFMA A-frags; B-frags from hpk (L2,
// amplification 128 MB total). 16 MFMA/step/wave. Each wave writes its own
// pacc/plsum slice (hf*4+ws) — no combine, no barrier anywhere.
__global__ __launch_bounds__(256, 2) void gat_flash_kernel(
    const unsigned char* __restrict__ msk, const unsigned short* __restrict__ hpk,
    const float* __restrict__ s1, const float* __restrict__ s2,
    float* __restrict__ pacc, float* __restrict__ plsum)
{
    const int tid  = threadIdx.x;
    const int lane = tid & 63;
    const int ws   = tid >> 6;
    const int i    = lane & 15;
    const int kb   = lane >> 4;
    const int hf   = blockIdx.x >> 7;    // k-split 0..3
    const int rb   = blockIdx.x & 127;   // row-block (64 rows)
    const int r0   = rb * BM;

    const unsigned char* mb0 = msk + ((size_t)(r0 +  0 + i) << 10) + hf * 256 + ws * 4 + kb;
    const unsigned char* mb1 = msk + ((size_t)(r0 + 16 + i) << 10) + hf * 256 + ws * 4 + kb;
    const unsigned char* mb2 = msk + ((size_t)(r0 + 32 + i) << 10) + hf * 256 + ws * 4 + kb;
    const unsigned char* mb3 = msk + ((size_t)(r0 + 48 + i) << 10) + hf * 256 + ws * 4 + kb;
    const float* s2b = s2 + hf * KSEG + ws * 32 + kb * 8;
    const unsigned short* hb = hpk + (((size_t)(hf * 64 + ws)) << 11) + (lane << 3);

    float eref[4];
#pragma unroll
    for (int ag = 0; ag < 4; ++ag) {
        int rg = r0 + ag * 16 + i;
        float e = s1[rg] + s2[rg];               // diagonal logit (adj[i][i]=1)
        eref[ag] = e > 0.f ? e : ALPHA * e;      // leaky_relu
    }
    float s1r[4];
#pragma unroll
    for (int ag = 0; ag < 4; ++ag) s1r[ag] = s1[r0 + ag * 16 + i];

    float lsum[4] = {0.f, 0.f, 0.f, 0.f};
    f32x4 acc[4][4];
#pragma unroll
    for (int ag = 0; ag < 4; ++ag)
#pragma unroll
        for (int dw = 0; dw < 4; ++dw) acc[ag][dw] = f32x4{0.f, 0.f, 0.f, 0.f};

    auto step = [&](const MSP& p, const UBP& u) {
        const float* sv0 = (const float*)&p.sA;
        const float* sv1 = (const float*)&p.sB;
        const uint4 ub[4] = {u.b0, u.b1, u.b2, u.b3};
#pragma unroll
        for (int ag = 0; ag < 4; ++ag) {
            float w[8];
#pragma unroll
            for (int z = 0; z < 4; ++z) {
                float e0 = s1r[ag] + sv0[z]; e0 = e0 > 0.f ? e0 : ALPHA * e0;
                float e1 = s1r[ag] + sv1[z]; e1 = e1 > 0.f ? e1 : ALPHA * e1;
                float w0 = __expf(e0 - eref[ag]);
                float w1 = __expf(e1 - eref[ag]);
                w[z]     = ((p.m[ag] >> z) & 1u)       ? w0 : 0.f;
                w[z + 4] = ((p.m[ag] >> (z + 4)) & 1u) ? w1 : 0.f;
            }
#pragma unroll
            for (int z = 0; z < 8; ++z) lsum[ag] += w[z];
            uint4 pk;
            pk.x = pk_bf16(w[0], w[1]); pk.y = pk_bf16(w[2], w[3]);
            pk.z = pk_bf16(w[4], w[5]); pk.w = pk_bf16(w[6], w[7]);
            bf16x8 A = __builtin_bit_cast(bf16x8, pk);
            acc[ag][0] = __builtin_amdgcn_mfma_f32_16x16x32_bf16(A, __builtin_bit_cast(bf16x8, ub[0]), acc[ag][0], 0, 0, 0);
            acc[ag][1] = __builtin_amdgcn_mfma_f32_16x16x32_bf16(A, __builtin_bit_cast(bf16x8, ub[1]), acc[ag][1], 0, 0, 0);
            acc[ag][2] = __builtin_amdgcn_mfma_f32_16x16x32_bf16(A, __builtin_bit_cast(bf16x8, ub[2]), acc[ag][2], 0, 0, 0);
            acc[ag][3] = __builtin_amdgcn_mfma_f32_16x16x32_bf16(A, __builtin_bit_cast(bf16x8, ub[3]), acc[ag][3], 0, 0, 0);
        }
    };

    MSP M0, M1; UBP U0, U1;
    issue_ms(M0, mb0, mb1, mb2, mb3, s2b, 0); issue_ub(U0, hb, 0);
    issue_ms(M1, mb0, mb1, mb2, mb3, s2b, 1); issue_ub(U1, hb, 1);
    for (int p = 0; p < NSH; p += 2) {
        step(M0, U0);
        if (p + 2 < NSH) { issue_ms(M0, mb0, mb1, mb2, mb3, s2b, p + 2); issue_ub(U0, hb, p + 2); }
        step(M1, U1);
        if (p + 3 < NSH) { issue_ms(M1, mb0, mb1, mb2, mb3, s2b, p + 3); issue_ub(U1, hb, p + 3); }
    }

    // lsum over kb sub-windows; lanes agreeing on i hold row ag*16+i
#pragma unroll
    for (int ag = 0; ag < 4; ++ag) {
        lsum[ag] += __shfl_xor(lsum[ag], 16, 64);
        lsum[ag] += __shfl_xor(lsum[ag], 32, 64);
    }
    const int sp = hf * 4 + ws;                  // private slice
    if (lane < 16) {
#pragma unroll
        for (int ag = 0; ag < 4; ++ag)
            plsum[(size_t)sp * N + r0 + ag * 16 + lane] = lsum[ag];
    }
    // C/D frag: row = kb*4+reg, col = dw*16+i
#pragma unroll
    for (int ag = 0; ag < 4; ++ag)
#pragma unroll
        for (int dw = 0; dw < 4; ++dw)
#pragma unroll
            for (int reg = 0; reg < 4; ++reg)
                pacc[((size_t)sp * N + r0 + ag * 16 + kb * 4 + reg) * 64 + dw * 16 + i]
                    = acc[ag][dw][reg];
}

// Kernel 3: combine the 16 slices, normalize, elu.
__global__ __launch_bounds__(256) void gat_reduce_kernel(
    const float* __restrict__ pacc, const float* __restrict__ plsum,
    float* __restrict__ out)
{
    int idx = blockIdx.x * 256 + threadIdx.x;    // over N*64
    int row = idx >> 6;
    float aa = 0.f, l = 0.f;
#pragma unroll
    for (int sp = 0; sp < NSLICE; ++sp) {
        aa += pacc[(size_t)sp * N * 64 + idx];
        l  += plsum[(size_t)sp * N + row];
    }
    float o = aa / l;
    out[idx] = o > 0.f ? o : expm1f(o);          // elu
}

extern "C" void kernel_launch(void* const* d_in, const int* in_sizes, int n_in,
                              void* d_out, int out_size, void* d_ws, size_t ws_size,
                              hipStream_t stream) {
    const float* input = (const float*)d_in[0];   // (8192, 512) f32
    const float* adj   = (const float*)d_in[1];   // (8192, 8192) f32
    const float* W     = (const float*)d_in[2];   // (512, 64) f32
    const float* a     = (const float*)d_in[3];   // (128, 1) f32
    float* out = (float*)d_out;                   // (8192, 64) f32

    unsigned short* hpk = (unsigned short*)d_ws;          // 1 MB fragment buffer
    float* s1    = (float*)(hpk + (size_t)N * D_OUT);     // N f32
    float* s2    = s1 + N;                                // N f32
    float* pacc  = s2 + N;                                // NSLICE*N*64 f32 = 32 MB
    float* plsum = pacc + (size_t)NSLICE * N * 64;        // NSLICE*N f32
    unsigned char* msk = (unsigned char*)(plsum + (size_t)NSLICE * N);  // 8 MB

    gat_mask_kernel<<<4096, 256, 0, stream>>>(adj, msk);
    gat_h_kernel<<<2048, 256, 0, stream>>>(input, W, a, hpk, s1, s2);
    gat_flash_kernel<<<128 * NSPLIT, 256, 0, stream>>>(msk, hpk, s1, s2, pacc, plsum);
    gat_reduce_kernel<<<N * 64 / 256, 256, 0, stream>>>(pacc, plsum, out);
}

// Round 12
// 118.618 us; speedup vs baseline: 7.8248x; 1.1795x over previous
//
#include <hip/hip_runtime.h>
#include <hip/hip_bf16.h>

#define N 8192
#define D_IN 512
#define D_OUT 64
#define ALPHA 0.2f
#define BM 16
#define NSPLIT 4
#define KSEG (N / NSPLIT)       // 2048 cols per split
#define NSH (KSEG / 128)        // 16 steps; each wave covers 32 cols/step
#define MLP 260                 // LDS mask row pitch (256 + 4 pad -> bank spread)

typedef __attribute__((ext_vector_type(4))) float f32x4;
typedef __attribute__((ext_vector_type(8))) short bf16x8;

static __device__ __forceinline__ unsigned pk_bf16(float lo, float hi) {
    unsigned ulo = __bfloat16_as_ushort(__float2bfloat16(lo));
    unsigned uhi = __bfloat16_as_ushort(__float2bfloat16(hi));
    return (uhi << 16) | ulo;
}

// Kernel 1: h = input @ W -> pre-swizzled MFMA B-frags (hpk) + s1/s2.
// K-split x4 across waves, LDS combine (verified R11). 2048 blocks.
__global__ __launch_bounds__(256) void gat_h_kernel(
    const float* __restrict__ input, const float* __restrict__ W,
    const float* __restrict__ a, unsigned short* __restrict__ hpk,
    float* __restrict__ s1, float* __restrict__ s2)
{
    __shared__ float hp[4][4][64];      // [ws][row][d] partials, 4 KB
    int ws   = threadIdx.x >> 6;
    int lane = threadIdx.x & 63;
    int row0 = blockIdx.x * 4;
    const float* in0 = input + (size_t)row0 * D_IN + ws * 128;
    const float* Wp  = W + ws * 128 * D_OUT;
    float acc[4] = {0.f, 0.f, 0.f, 0.f};
#pragma unroll 4
    for (int k = 0; k < 128; ++k) {
        float wk = Wp[k * D_OUT + lane];
#pragma unroll
        for (int r = 0; r < 4; ++r)
            acc[r] = fmaf(in0[r * D_IN + k], wk, acc[r]);   // in0 wave-uniform
    }
#pragma unroll
    for (int r = 0; r < 4; ++r) hp[ws][r][lane] = acc[r];
    __syncthreads();
    if (ws == 0) {
        float h[4];
#pragma unroll
        for (int r = 0; r < 4; ++r)
            h[r] = (hp[0][r][lane] + hp[1][r][lane]) + (hp[2][r][lane] + hp[3][r][lane]);
        // hpk fragment store: element (j,d) -> ((kw*4+dw)*64 + kb*16+dd)*8 + e
        int kw = row0 >> 5, kb = (row0 >> 3) & 3, e0 = row0 & 7;
        int dw = lane >> 4, dd = lane & 15;
        size_t off = ((size_t)((kw * 4 + dw) * 64) + kb * 16 + dd) * 8 + e0;
        uint2 hv;
        hv.x = pk_bf16(h[0], h[1]);
        hv.y = pk_bf16(h[2], h[3]);
        *(uint2*)(hpk + off) = hv;
        float a1 = a[lane], a2 = a[D_OUT + lane];
#pragma unroll
        for (int r = 0; r < 4; ++r) {
            float p1 = h[r] * a1;
            float p2 = h[r] * a2;
#pragma unroll
            for (int off2 = 32; off2; off2 >>= 1) {
                p1 += __shfl_xor(p1, off2, 64);
                p2 += __shfl_xor(p2, off2, 64);
            }
            if (lane == 0) { s1[row0 + r] = p1; s2[row0 + r] = p2; }
        }
    }
}

struct SSP { float4 sA, sB; };          // s2 pair for one 32-col slice
struct UBP { uint4 b0, b1, b2, b3; };   // 4 d-window B-frags for one 32-k window

static __device__ __forceinline__ void issue_s(SSP& p, const float* sb, int ps) {
    p.sA = *(const float4*)(sb + ps * 128);
    p.sB = *(const float4*)(sb + ps * 128 + 4);
}
static __device__ __forceinline__ void issue_ub(UBP& p, const unsigned short* hb,
                                                int ps) {
    const unsigned short* f = hb + ((size_t)ps << 13);
    p.b0 = *(const uint4*)(f);
    p.b1 = *(const uint4*)(f + 512);
    p.b2 = *(const uint4*)(f + 1024);
    p.b3 = *(const uint4*)(f + 1536);
}

// Kernel 2 (FUSED): pass 1 streams the block's 16x2048 adj quarter COALESCED
// (8 independent 1KB loads in flight/wave, no dependent compute) -> 1 bit/elem
// into padded LDS. ONE barrier. Pass 2 = R9's verified MFMA loop, mask from
// LDS (conflict-free), s2/hpk 2-deep reg prefetch (L1/L2). In-block combine,
// split-K x4 partials out.
__global__ __launch_bounds__(256, 4) void gat_flash_kernel(
    const float* __restrict__ adj, const unsigned short* __restrict__ hpk,
    const float* __restrict__ s1, const float* __restrict__ s2,
    float* __restrict__ pacc, float* __restrict__ plsum)
{
    __shared__ unsigned char ml[BM * MLP];   // 4.2 KB mask bits
    __shared__ float Cl[4][BM][D_OUT];       // 16 KB combine
    __shared__ float lsl[4][BM];

    const int tid  = threadIdx.x;
    const int lane = tid & 63;
    const int ws   = tid >> 6;
    const int i    = lane & 15;          // row within tile (A-frag row)
    const int kb   = lane >> 4;          // k-subwindow within 32
    const int hf   = blockIdx.x >> 9;    // k-split 0..3
    const int rb   = blockIdx.x & 511;   // row-block
    const int rg   = rb * BM + i;

    // ---- pass 1: coalesced adj stream -> LDS mask bits ----
#pragma unroll
    for (int g = 0; g < 4; ++g) {
        int r = ws * 4 + g;
        const float* rowp = adj + (size_t)(rb * BM + r) * N + hf * KSEG + lane * 8;
        float4 v[8];
#pragma unroll
        for (int c = 0; c < 4; ++c) {
            v[2 * c]     = *(const float4*)(rowp + c * 512);
            v[2 * c + 1] = *(const float4*)(rowp + c * 512 + 4);
        }
#pragma unroll
        for (int c = 0; c < 4; ++c) {
            float4 v0 = v[2 * c], v1 = v[2 * c + 1];
            unsigned b =  (unsigned)(v0.x > 0.f)
                       | ((unsigned)(v0.y > 0.f) << 1)
                       | ((unsigned)(v0.z > 0.f) << 2)
                       | ((unsigned)(v0.w > 0.f) << 3)
                       | ((unsigned)(v1.x > 0.f) << 4)
                       | ((unsigned)(v1.y > 0.f) << 5)
                       | ((unsigned)(v1.z > 0.f) << 6)
                       | ((unsigned)(v1.w > 0.f) << 7);
            ml[r * MLP + c * 64 + lane] = (unsigned char)b;
        }
    }
    __syncthreads();

    // ---- pass 2: 16-step MFMA loop (R9 structure, mask from LDS) ----
    const float* s2b = s2 + hf * KSEG + ws * 32 + kb * 8;
    const unsigned short* hb = hpk + (((size_t)(hf * 64 + ws)) << 11) + (lane << 3);
    const unsigned char* mlb = ml + i * MLP + ws * 4 + kb;

    float s1r  = s1[rg];
    float eref = s1r + s2[rg];                    // diagonal logit (adj[i][i]=1)
    eref = eref > 0.f ? eref : ALPHA * eref;      // leaky_relu
    float lsum = 0.f;
    f32x4 acc0 = {0,0,0,0}, acc1 = {0,0,0,0}, acc2 = {0,0,0,0}, acc3 = {0,0,0,0};

    auto step = [&](const SSP& p, const UBP& u, unsigned m) {
        const float* sv0 = (const float*)&p.sA;
        const float* sv1 = (const float*)&p.sB;
        float w[8];
#pragma unroll
        for (int z = 0; z < 4; ++z) {
            float e0 = s1r + sv0[z]; e0 = e0 > 0.f ? e0 : ALPHA * e0;   // leaky_relu
            float e1 = s1r + sv1[z]; e1 = e1 > 0.f ? e1 : ALPHA * e1;
            float w0 = __expf(e0 - eref);
            float w1 = __expf(e1 - eref);
            w[z]     = ((m >> z) & 1u)       ? w0 : 0.f;
            w[z + 4] = ((m >> (z + 4)) & 1u) ? w1 : 0.f;
        }
#pragma unroll
        for (int z = 0; z < 8; ++z) lsum += w[z];
        uint4 pk;
        pk.x = pk_bf16(w[0], w[1]); pk.y = pk_bf16(w[2], w[3]);
        pk.z = pk_bf16(w[4], w[5]); pk.w = pk_bf16(w[6], w[7]);
        bf16x8 A = __builtin_bit_cast(bf16x8, pk);
        acc0 = __builtin_amdgcn_mfma_f32_16x16x32_bf16(A, __builtin_bit_cast(bf16x8, u.b0), acc0, 0, 0, 0);
        acc1 = __builtin_amdgcn_mfma_f32_16x16x32_bf16(A, __builtin_bit_cast(bf16x8, u.b1), acc1, 0, 0, 0);
        acc2 = __builtin_amdgcn_mfma_f32_16x16x32_bf16(A, __builtin_bit_cast(bf16x8, u.b2), acc2, 0, 0, 0);
        acc3 = __builtin_amdgcn_mfma_f32_16x16x32_bf16(A, __builtin_bit_cast(bf16x8, u.b3), acc3, 0, 0, 0);
    };

    SSP S0, S1; UBP U0, U1;
    issue_s(S0, s2b, 0); issue_ub(U0, hb, 0);
    issue_s(S1, s2b, 1); issue_ub(U1, hb, 1);
    for (int p = 0; p < NSH; p += 2) {
        unsigned m0 = mlb[p * 16];
        step(S0, U0, m0);
        if (p + 2 < NSH) { issue_s(S0, s2b, p + 2); issue_ub(U0, hb, p + 2); }
        unsigned m1 = mlb[(p + 1) * 16];
        step(S1, U1, m1);
        if (p + 3 < NSH) { issue_s(S1, s2b, p + 3); issue_ub(U1, hb, p + 3); }
    }

    // lsum: lanes i, i+16, i+32, i+48 hold row-i k-slices of this wave
    lsum += __shfl_xor(lsum, 16, 64);
    lsum += __shfl_xor(lsum, 32, 64);
    if (lane < 16) lsl[ws][lane] = lsum;

    // C k-partials: row = kb*4+reg, col = dw*16+i  (C/D frag layout)
    const f32x4 av[4] = {acc0, acc1, acc2, acc3};
#pragma unroll
    for (int dw = 0; dw < 4; ++dw)
#pragma unroll
        for (int reg = 0; reg < 4; ++reg)
            Cl[ws][kb * 4 + reg][dw * 16 + i] = av[dw][reg];
    __syncthreads();

#pragma unroll
    for (int o = tid; o < BM * D_OUT; o += 256) {
        int row = o >> 6, d = o & 63;
        float v = (Cl[0][row][d] + Cl[1][row][d]) + (Cl[2][row][d] + Cl[3][row][d]);
        pacc[((size_t)hf * N + rb * BM + row) * 64 + d] = v;
    }
    if (tid < BM)
        plsum[hf * N + rb * BM + tid] =
            (lsl[0][tid] + lsl[1][tid]) + (lsl[2][tid] + lsl[3][tid]);
}

// Kernel 3: combine the 4 k-splits, normalize, elu.
__global__ __launch_bounds__(256) void gat_reduce_kernel(
    const float* __restrict__ pacc, const float* __restrict__ plsum,
    float* __restrict__ out)
{
    int idx = blockIdx.x * 256 + threadIdx.x;    // over N*64
    int row = idx >> 6;
    float aa = 0.f, l = 0.f;
#pragma unroll
    for (int hf = 0; hf < NSPLIT; ++hf) {
        aa += pacc[(size_t)hf * N * 64 + idx];
        l  += plsum[hf * N + row];
    }
    float o = aa / l;
    out[idx] = o > 0.f ? o : expm1f(o);          // elu
}

extern "C" void kernel_launch(void* const* d_in, const int* in_sizes, int n_in,
                              void* d_out, int out_size, void* d_ws, size_t ws_size,
                              hipStream_t stream) {
    const float* input = (const float*)d_in[0];   // (8192, 512) f32
    const float* adj   = (const float*)d_in[1];   // (8192, 8192) f32
    const float* W     = (const float*)d_in[2];   // (512, 64) f32
    const float* a     = (const float*)d_in[3];   // (128, 1) f32
    float* out = (float*)d_out;                   // (8192, 64) f32

    unsigned short* hpk = (unsigned short*)d_ws;          // 1 MB fragment buffer
    float* s1    = (float*)(hpk + (size_t)N * D_OUT);     // N f32
    float* s2    = s1 + N;                                // N f32
    float* pacc  = s2 + N;                                // NSPLIT*N*64 f32 = 8 MB
    float* plsum = pacc + (size_t)NSPLIT * N * 64;        // NSPLIT*N f32

    gat_h_kernel<<<2048, 256, 0, stream>>>(input, W, a, hpk, s1, s2);
    gat_flash_kernel<<<512 * NSPLIT, 256, 0, stream>>>(adj, hpk, s1, s2, pacc, plsum);
    gat_reduce_kernel<<<N * 64 / 256, 256, 0, stream>>>(pacc, plsum, out);
}